// Round 5
// baseline (537.025 us; speedup 1.0000x reference)
//
#include <hip/hip_runtime.h>
#include <hip/hip_bf16.h>
#include <cstddef>

typedef __attribute__((ext_vector_type(8))) short short8;
typedef __attribute__((ext_vector_type(4))) float fx4;
typedef __attribute__((ext_vector_type(4))) unsigned short us4;
typedef __attribute__((ext_vector_type(8))) unsigned short us8;

constexpr int BATCH = 64;

static __device__ __forceinline__ unsigned short f2bf(float x) {
    __hip_bfloat16 h = __float2bfloat16(x);
    return *reinterpret_cast<unsigned short*>(&h);
}

// ---------------------------------------------------------------------------
// conv0: CIN=3 fp32 VALU conv + relu + pool, emits NHWC bf16 [64][32][32][64]
// ---------------------------------------------------------------------------
__global__ __launch_bounds__(256)
void conv0_kernel(const float* __restrict__ x, const float* __restrict__ w,
                  const float* __restrict__ bias, unsigned short* __restrict__ out)
{
    __shared__ float ins[3][18][19];
    const int tid  = threadIdx.x;
    const int lane = tid & 63;
    const int wv   = __builtin_amdgcn_readfirstlane(tid >> 6);
    const int img  = blockIdx.x >> 4;
    const int tile = blockIdx.x & 15;
    const int ty0  = (tile >> 2) * 16, tx0 = (tile & 3) * 16;
    const int py0  = (lane >> 3) * 2,  px0 = (lane & 7) * 2;
    const int co0  = wv * 16;

    for (int t = tid; t < 3*18*18; t += 256) {
        int xx = t % 18, yy = (t/18) % 18, ci = t/(18*18);
        int gy = ty0 + yy - 1, gx = tx0 + xx - 1;
        float v = 0.f;
        if (gy >= 0 && gy < 64 && gx >= 0 && gx < 64)
            v = x[((img*3 + ci)*64 + gy)*64 + gx];
        ins[ci][yy][xx] = v;
    }
    __syncthreads();

    float acc[16][4];
    #pragma unroll
    for (int j = 0; j < 16; j++)
        #pragma unroll
        for (int r = 0; r < 4; r++) acc[j][r] = 0.f;

    #pragma unroll
    for (int ci = 0; ci < 3; ci++) {
        float p[4][4];
        #pragma unroll
        for (int dy = 0; dy < 4; dy++)
            #pragma unroll
            for (int dx = 0; dx < 4; dx++)
                p[dy][dx] = ins[ci][py0+dy][px0+dx];
        #pragma unroll
        for (int j = 0; j < 16; j++) {
            const float* wp = w + ((co0+j)*3 + ci)*9;
            float w0=wp[0],w1=wp[1],w2=wp[2],w3=wp[3],w4=wp[4],
                  w5=wp[5],w6=wp[6],w7=wp[7],w8=wp[8];
            #pragma unroll
            for (int oy = 0; oy < 2; oy++)
                #pragma unroll
                for (int ox = 0; ox < 2; ox++)
                    acc[j][oy*2+ox] +=
                        p[oy+0][ox+0]*w0 + p[oy+0][ox+1]*w1 + p[oy+0][ox+2]*w2 +
                        p[oy+1][ox+0]*w3 + p[oy+1][ox+1]*w4 + p[oy+1][ox+2]*w5 +
                        p[oy+2][ox+0]*w6 + p[oy+2][ox+1]*w7 + p[oy+2][ox+2]*w8;
        }
    }

    us8 v0, v1;
    #pragma unroll
    for (int j = 0; j < 16; j++) {
        float m = fmaxf(fmaxf(acc[j][0], acc[j][1]), fmaxf(acc[j][2], acc[j][3]));
        unsigned short u = f2bf(fmaxf(m + bias[co0+j], 0.f));
        if (j < 8) v0[j] = u; else v1[j-8] = u;
    }
    int oy = (ty0+py0) >> 1, ox = (tx0+px0) >> 1;
    unsigned short* o = &out[((size_t)(img*32+oy)*32 + ox)*64 + co0];
    *(us8*)(o)     = v0;
    *(us8*)(o + 8) = v1;
}

// ---------------------------------------------------------------------------
// Weight prepack: fp32 [CO][CI][3][3] -> bf16 [tap][ci/32][co][32]
// ---------------------------------------------------------------------------
struct PPAll {
    const float* src[7];
    unsigned long long dstoff[7];
    int cin[7];
    int cout[7];
    int end[7];
};

__global__ __launch_bounds__(256)
void prepack(PPAll a, unsigned short* __restrict__ wpbase)
{
    int t = blockIdx.x*256 + threadIdx.x;
    if (t >= 1024000) return;
    int l = 0;
    while (t >= a.end[l]) l++;
    int start = (l == 0) ? 0 : a.end[l-1];
    int local = t - start;
    int cin = a.cin[l], cout = a.cout[l];
    int co = local / cin, ci = local % cin;
    const float* s = a.src[l] + (size_t)local * 9;
    unsigned short* d = wpbase + a.dstoff[l];
    int kct = cin >> 5;
    #pragma unroll
    for (int k = 0; k < 9; k++)
        d[((size_t)(k*kct + (ci >> 5))*cout + co)*32 + (ci & 31)] = f2bf(s[k]);
}

// ---------------------------------------------------------------------------
// MFMA conv: implicit GEMM per tap. Wave tile = 64 co x 32 px (NF=2).
// Regions: P==1 -> RYxRX pixel patch of one image; P>1 -> P whole HxH images.
// Stage full CIN/KS slice once (one barrier), barrier-free MFMA loop.
// 4096 waves per conv = 16 waves/CU.
// ---------------------------------------------------------------------------
template<int CIN, int COUT, int H, int CW, int SW, int P, int RY, int RX, int KS, bool POOL>
__global__ __launch_bounds__(256, 4)
void conv_mfma(const unsigned short* __restrict__ in, const unsigned short* __restrict__ wp,
               const float* __restrict__ bias, void* __restrict__ outp)
{
    constexpr int HY   = RY + 2, HX = RX + 2;
    constexpr int KCT  = CIN / 32;
    constexpr int CINS = CIN / KS;
    constexpr int KC   = CINS / 32;
    constexpr int PADW = (CINS == 128) ? 24 : 8;
    constexpr int STR  = CINS + PADW;
    static_assert(CW * SW == 4, "4 waves");
    static_assert(P * RY * RX == 32, "N=32 wave tile");

    __shared__ unsigned short ins[SW][P][HY][HX][STR];

    const int tid  = threadIdx.x;
    const int lane = tid & 63;
    const int wv   = __builtin_amdgcn_readfirstlane(tid >> 6);
    const int quad = lane >> 4;
    const int nn   = lane & 15;
    const int cg   = wv % CW;
    const int sg   = wv / CW;
    const int co0  = (blockIdx.y * CW + cg) * 64;
    const int ks   = (KS > 1) ? (int)blockIdx.z : 0;

    auto decode = [&](int rg, int& img, int& y0, int& x0) {
        if constexpr (P == 1) {
            constexpr int REG = (H/RY)*(H/RX);
            constexpr int RXN = H/RX;
            img = rg / REG;
            int rs = rg % REG;
            y0 = (rs / RXN) * RY;
            x0 = (rs % RXN) * RX;
        } else {
            img = rg * P; y0 = 0; x0 = 0;
        }
    };

    int w_img, w_y0, w_x0;
    decode(blockIdx.x * SW + sg, w_img, w_y0, w_x0);

    // ---- stage all CINS channels, one barrier ----
    {
        constexpr int E = SW*P*HY*HX*(CINS/8);
        for (int u = tid; u < E; u += 256) {
            int q   = u % (CINS/8);
            int pix = u / (CINS/8);
            int xx  = pix % HX;
            int yy  = (pix / HX) % HY;
            int pp  = (pix / (HX*HY)) % P;
            int ss  = pix / (HX*HY*P);
            int s_img, s_y0, s_x0;
            decode(blockIdx.x * SW + ss, s_img, s_y0, s_x0);
            int gy = s_y0 + yy - 1, gx = s_x0 + xx - 1;
            int imgp = s_img + ((P == 1) ? 0 : pp);
            us8 v;
            #pragma unroll
            for (int e = 0; e < 8; e++) v[e] = 0;
            if (gy >= 0 && gy < H && gx >= 0 && gx < H)
                v = *(const us8*)&in[(((size_t)imgp*H + gy)*H + gx)*CIN + ks*CINS + q*8];
            *(us8*)&ins[ss][pp][yy][xx][q*8] = v;
        }
    }
    __syncthreads();

    fx4 acc[4][2];
    #pragma unroll
    for (int mf = 0; mf < 4; mf++)
        #pragma unroll
        for (int nf = 0; nf < 2; nf++) {
            fx4 z = {0.f, 0.f, 0.f, 0.f};
            acc[mf][nf] = z;
        }

    // ---- barrier-free MFMA loop ----
    #pragma unroll 1
    for (int kc = 0; kc < KC; kc++) {
        #pragma unroll 3
        for (int tap = 0; tap < 9; tap++) {
            const int dy = tap / 3, dx = tap % 3;
            const unsigned short* wb =
                wp + ((size_t)(tap*KCT + ks*KC + kc)*COUT + co0 + nn)*32 + quad*8;
            short8 a[4];
            #pragma unroll
            for (int mf = 0; mf < 4; mf++)
                a[mf] = *(const short8*)(wb + (size_t)mf*16*32);
            short8 b[2];
            #pragma unroll
            for (int nf = 0; nf < 2; nf++) {
                int pp, py, px;
                if constexpr (P == 1) { pp = 0;  py = nf*4 + (nn>>2); px = nn & 3; }
                else                  { pp = nf; py = nn>>2;          px = nn & 3; }
                b[nf] = *(const short8*)&ins[sg][pp][py+dy][px+dx][kc*32 + quad*8];
            }
            #pragma unroll
            for (int mf = 0; mf < 4; mf++)
                #pragma unroll
                for (int nf = 0; nf < 2; nf++)
                    acc[mf][nf] = __builtin_amdgcn_mfma_f32_16x16x32_bf16(
                        a[mf], b[nf], acc[mf][nf], 0, 0, 0);
        }
    }

    if constexpr (KS > 1) {
        float* part = (float*)outp;
        constexpr size_t NPIX = (size_t)BATCH * H * H;
        #pragma unroll
        for (int mf = 0; mf < 4; mf++)
            #pragma unroll
            for (int nf = 0; nf < 2; nf++) {
                int img, py, px;
                if constexpr (P == 1) { img = w_img;      py = w_y0 + nf*4 + (nn>>2); px = w_x0 + (nn&3); }
                else                  { img = w_img + nf; py = nn>>2;                 px = nn&3; }
                size_t npix = (size_t)img*H*H + py*H + px;
                size_t idx  = ((size_t)ks*NPIX + npix)*COUT + co0 + mf*16 + quad*4;
                *(fx4*)&part[idx] = acc[mf][nf];
            }
    } else if constexpr (POOL) {
        unsigned short* out = (unsigned short*)outp;
        constexpr int HO = H/2;
        #pragma unroll
        for (int mf = 0; mf < 4; mf++) {
            fx4 b4 = *(const fx4*)&bias[co0 + mf*16 + quad*4];
            #pragma unroll
            for (int nf = 0; nf < 2; nf++) {
                us4 o;
                #pragma unroll
                for (int r = 0; r < 4; r++) {
                    float v = acc[mf][nf][r];
                    v = fmaxf(v, __shfl_xor(v, 1));
                    v = fmaxf(v, __shfl_xor(v, 4));
                    o[r] = f2bf(fmaxf(v + b4[r], 0.f));
                }
                if ((nn & 5) == 0) {
                    int img, py, px;
                    if constexpr (P == 1) { img = w_img;      py = w_y0 + nf*4 + (nn>>2); px = w_x0 + (nn&3); }
                    else                  { img = w_img + nf; py = nn>>2;                 px = nn&3; }
                    size_t idx = (((size_t)img*HO + (py>>1))*HO + (px>>1))*COUT
                               + co0 + mf*16 + quad*4;
                    *(us4*)&out[idx] = o;
                }
            }
        }
    } else {
        unsigned short* out = (unsigned short*)outp;
        #pragma unroll
        for (int mf = 0; mf < 4; mf++) {
            fx4 b4 = *(const fx4*)&bias[co0 + mf*16 + quad*4];
            #pragma unroll
            for (int nf = 0; nf < 2; nf++) {
                us4 o;
                #pragma unroll
                for (int r = 0; r < 4; r++)
                    o[r] = f2bf(fmaxf(acc[mf][nf][r] + b4[r], 0.f));
                int img, py, px;
                if constexpr (P == 1) { img = w_img;      py = w_y0 + nf*4 + (nn>>2); px = w_x0 + (nn&3); }
                else                  { img = w_img + nf; py = nn>>2;                 px = nn&3; }
                size_t idx = (((size_t)img*H + py)*H + px)*COUT + co0 + mf*16 + quad*4;
                *(us4*)&out[idx] = o;
            }
        }
    }
}

// ---------------------------------------------------------------------------
// In-place K-slice reduction: group g sums slices {4g*STRIDE + j*STRIDE},
// j=0..3, into slice 4g*STRIDE. Thread per fx4, fully coalesced.
// ---------------------------------------------------------------------------
template<int NELEM, int GROUPS, int STRIDE>
__global__ __launch_bounds__(256)
void ksum4(float* __restrict__ p)
{
    int t = blockIdx.x*256 + threadIdx.x;
    if (t >= GROUPS*(NELEM/4)) return;
    int g = t / (NELEM/4);
    int i = (t % (NELEM/4)) * 4;
    fx4 s = {0.f,0.f,0.f,0.f};
    #pragma unroll
    for (int j = 0; j < 4; j++)
        s += *(const fx4*)&p[(size_t)((g*4 + j)*STRIDE)*NELEM + i];
    *(fx4*)&p[(size_t)(g*4*STRIDE)*NELEM + i] = s;
}

// ---------------------------------------------------------------------------
// Combine kernels (read KS remaining slices)
// ---------------------------------------------------------------------------
template<int KS, int NPIX, int CO>
__global__ __launch_bounds__(256)
void combine_nhwc(const float* __restrict__ part, const float* __restrict__ bias,
                  unsigned short* __restrict__ out)
{
    constexpr int C4 = CO/4;
    int t = blockIdx.x*256 + threadIdx.x;
    if (t >= NPIX*C4) return;
    int c4 = t % C4, pix = t / C4;
    fx4 s = *(const fx4*)&bias[c4*4];
    #pragma unroll
    for (int k = 0; k < KS; k++)
        s += *(const fx4*)&part[((size_t)k*NPIX + pix)*CO + c4*4];
    us4 o;
    #pragma unroll
    for (int r = 0; r < 4; r++) o[r] = f2bf(fmaxf(s[r], 0.f));
    *(us4*)&out[(size_t)pix*CO + c4*4] = o;
}

template<int KS, int HI, int CO>
__global__ __launch_bounds__(256)
void combine_pool(const float* __restrict__ part, const float* __restrict__ bias,
                  unsigned short* __restrict__ out)
{
    constexpr int HO = HI/2, C4 = CO/4;
    constexpr size_t NPIX = (size_t)BATCH*HI*HI;
    int t = blockIdx.x*256 + threadIdx.x;
    if (t >= BATCH*HO*HO*C4) return;
    int c4 = t % C4;
    int r  = t / C4;
    int xo = r % HO, yo = (r/HO) % HO, img = r/(HO*HO);
    fx4 m = {-1e30f, -1e30f, -1e30f, -1e30f};
    #pragma unroll
    for (int iy = 0; iy < 2; iy++)
        #pragma unroll
        for (int ix = 0; ix < 2; ix++) {
            size_t pix = (size_t)img*HI*HI + (2*yo+iy)*HI + (2*xo+ix);
            fx4 s = {0.f,0.f,0.f,0.f};
            #pragma unroll
            for (int k = 0; k < KS; k++)
                s += *(const fx4*)&part[((size_t)k*NPIX + pix)*CO + c4*4];
            #pragma unroll
            for (int e = 0; e < 4; e++) m[e] = fmaxf(m[e], s[e]);
        }
    fx4 b4 = *(const fx4*)&bias[c4*4];
    us4 o;
    #pragma unroll
    for (int e = 0; e < 4; e++) o[e] = f2bf(fmaxf(m[e] + b4[e], 0.f));
    *(us4*)&out[((size_t)(img*HO+yo)*HO + xo)*CO + c4*4] = o;
}

// conv4b finish (after ksum tree): slice 0 + bias + relu + mask + pool2
// -> X0 bf16 [64][2048]
__global__ __launch_bounds__(256)
void combine4b(const float* __restrict__ part, const float* __restrict__ bias,
               const float* __restrict__ mask, unsigned short* __restrict__ X0)
{
    int t = blockIdx.x*256 + threadIdx.x;
    if (t >= BATCH*512) return;
    int b = t / 512, c = t % 512;
    float s[16];
    #pragma unroll
    for (int p = 0; p < 16; p++)
        s[p] = part[(size_t)(b*16 + p)*512 + c];
    float mk = mask[b*512 + c], bb = bias[c];
    us4 o;
    #pragma unroll
    for (int py = 0; py < 2; py++)
        #pragma unroll
        for (int px = 0; px < 2; px++) {
            float m = fmaxf(fmaxf(s[(2*py)*4 + 2*px],     s[(2*py)*4 + 2*px+1]),
                            fmaxf(s[(2*py+1)*4 + 2*px],   s[(2*py+1)*4 + 2*px+1]));
            o[py*2+px] = f2bf(mk * fmaxf(m + bb, 0.f));
        }
    *(us4*)&X0[(size_t)b*2048 + c*4] = o;
}

// ---------------------------------------------------------------------------
// engram mask
// ---------------------------------------------------------------------------
__global__ void build_mask(const int* __restrict__ y, const int* __restrict__ btab,
                           float* __restrict__ mask)
{
    __shared__ float m[512];
    int b = blockIdx.x;
    int t = threadIdx.x;               // 128 threads
    for (int i = t; i < 512; i += 128) m[i] = 0.f;
    __syncthreads();
    int cls = y[b];
    int idx = btab[cls*128 + t];
    m[idx] = 1.0f;
    __syncthreads();
    for (int i = t; i < 512; i += 128) mask[b*512 + i] = m[i];
}

// ---------------------------------------------------------------------------
// MFMA FC: C[64,N] = X[64,K](bf16) @ W[N,K]^T(fp32 -> bf16 in-register).
// ---------------------------------------------------------------------------
template<int K, int NP, int NREAL, int KSO>
__global__ __launch_bounds__(256)
void fc_mfma(const unsigned short* __restrict__ X, const float* __restrict__ W,
             float* __restrict__ P)
{
    constexpr int KW = K / (KSO*4);
    constexpr int NI = KW / 32;
    __shared__ alignas(16) unsigned short XL[4][64][40];
    __shared__ alignas(16) float R[64][68];

    const int tid  = threadIdx.x;
    const int lane = tid & 63;
    const int wv   = __builtin_amdgcn_readfirstlane(tid >> 6);
    const int quad = lane >> 4;
    const int nn   = lane & 15;
    const int c0   = blockIdx.x * 64;
    const int ksb  = blockIdx.y;
    const int k0   = (ksb*4 + wv) * KW;

    fx4 acc[4][4];
    #pragma unroll
    for (int mf = 0; mf < 4; mf++)
        #pragma unroll
        for (int nf = 0; nf < 4; nf++) {
            fx4 z = {0.f,0.f,0.f,0.f};
            acc[mf][nf] = z;
        }

    #pragma unroll
    for (int kc = 0; kc < NI; kc++) {
        const int kw = k0 + kc*32;
        const unsigned short* xp = X + (size_t)lane*K + kw;
        us8 x0 = *(const us8*)(xp);
        us8 x1 = *(const us8*)(xp + 8);
        us8 x2 = *(const us8*)(xp + 16);
        us8 x3 = *(const us8*)(xp + 24);
        *(us8*)&XL[wv][lane][0]  = x0;
        *(us8*)&XL[wv][lane][8]  = x1;
        *(us8*)&XL[wv][lane][16] = x2;
        *(us8*)&XL[wv][lane][24] = x3;
        short8 b[4];
        #pragma unroll
        for (int nf = 0; nf < 4; nf++) {
            int c = c0 + nf*16 + nn;
            if (c > NREAL-1) c = NREAL-1;
            const float* wp = W + (size_t)c*K + kw + quad*8;
            float4 f0 = *(const float4*)(wp);
            float4 f1 = *(const float4*)(wp + 4);
            short8 t;
            t[0] = (short)f2bf(f0.x); t[1] = (short)f2bf(f0.y);
            t[2] = (short)f2bf(f0.z); t[3] = (short)f2bf(f0.w);
            t[4] = (short)f2bf(f1.x); t[5] = (short)f2bf(f1.y);
            t[6] = (short)f2bf(f1.z); t[7] = (short)f2bf(f1.w);
            b[nf] = t;
        }
        short8 a[4];
        #pragma unroll
        for (int mf = 0; mf < 4; mf++)
            a[mf] = *(const short8*)&XL[wv][mf*16 + nn][quad*8];
        #pragma unroll
        for (int mf = 0; mf < 4; mf++)
            #pragma unroll
            for (int nf = 0; nf < 4; nf++)
                acc[mf][nf] = __builtin_amdgcn_mfma_f32_16x16x32_bf16(
                    a[mf], b[nf], acc[mf][nf], 0, 0, 0);
    }

    for (int ww = 0; ww < 4; ww++) {
        __syncthreads();
        if (wv == ww) {
            #pragma unroll
            for (int mf = 0; mf < 4; mf++)
                #pragma unroll
                for (int nf = 0; nf < 4; nf++) {
                    int n = nf*16 + nn;
                    #pragma unroll
                    for (int r = 0; r < 4; r++) {
                        int m = mf*16 + quad*4 + r;
                        float v = acc[mf][nf][r];
                        if (ww) v += R[m][n];
                        R[m][n] = v;
                    }
                }
        }
    }
    __syncthreads();
    {
        int m  = tid >> 2;
        int n0 = (tid & 3) * 16;
        float* dst = P + ((size_t)ksb*64 + m)*NP + c0 + n0;
        #pragma unroll
        for (int j = 0; j < 4; j++) {
            fx4 v = *(const fx4*)&R[m][n0 + j*4];
            *(fx4*)(dst + j*4) = v;
        }
    }
}

template<int N, int KS>
__global__ __launch_bounds__(256)
void fc_combine_bf16(const float* __restrict__ P, const float* __restrict__ bias,
                     unsigned short* __restrict__ Xo)
{
    int t = blockIdx.x*256 + threadIdx.x;
    if (t >= 64*(N/4)) return;
    int c4 = t % (N/4);
    int b  = t / (N/4);
    fx4 s = *(const fx4*)&bias[c4*4];
    #pragma unroll
    for (int ks = 0; ks < KS; ks++)
        s += *(const fx4*)&P[((size_t)ks*64 + b)*N + c4*4];
    us4 o;
    #pragma unroll
    for (int r = 0; r < 4; r++) o[r] = f2bf(fmaxf(s[r], 0.f));
    *(us4*)&Xo[(size_t)b*N + c4*4] = o;
}

// fc3 finish after ksum4 groups: sum slices {0,4,...,28}
__global__ __launch_bounds__(256)
void fc3_combine(const float* __restrict__ P, const float* __restrict__ bias,
                 float* __restrict__ out)
{
    int t = blockIdx.x*256 + threadIdx.x;
    if (t >= 64*1000) return;
    int b = t / 1000, c = t % 1000;
    float s = bias[c];
    #pragma unroll
    for (int ks = 0; ks < 8; ks++)
        s += P[((size_t)(ks*4)*64 + b)*1024 + c];
    out[t] = s;
}

// ---------------------------------------------------------------------------
extern "C" void kernel_launch(void* const* d_in, const int* in_sizes, int n_in,
                              void* d_out, int out_size, void* d_ws, size_t ws_size,
                              hipStream_t stream)
{
    const float* x    = (const float*)d_in[0];
    const int*   y    = (const int*)  d_in[1];
    const int*   btab = (const int*)  d_in[2];
    const float* cw0  = (const float*)d_in[3];  const float* cb0  = (const float*)d_in[4];
    const float* cw1  = (const float*)d_in[5];  const float* cb1  = (const float*)d_in[6];
    const float* cw2a = (const float*)d_in[7];  const float* cb2a = (const float*)d_in[8];
    const float* cw2b = (const float*)d_in[9];  const float* cb2b = (const float*)d_in[10];
    const float* cw3a = (const float*)d_in[11]; const float* cb3a = (const float*)d_in[12];
    const float* cw3b = (const float*)d_in[13]; const float* cb3b = (const float*)d_in[14];
    const float* cw4a = (const float*)d_in[15]; const float* cb4a = (const float*)d_in[16];
    const float* cw4b = (const float*)d_in[17]; const float* cb4b = (const float*)d_in[18];
    const float* fw1  = (const float*)d_in[19]; const float* fb1  = (const float*)d_in[20];
    const float* fw2  = (const float*)d_in[21]; const float* fb2  = (const float*)d_in[22];
    const float* fw3  = (const float*)d_in[23]; const float* fb3  = (const float*)d_in[24];
    (void)in_sizes; (void)n_in; (void)out_size; (void)ws_size;

    float* ws = (float*)d_ws;
    unsigned short* ActA = (unsigned short*)(ws);             // 2,097,152 f region
    unsigned short* ActB = (unsigned short*)(ws + 2097152);   // 1,048,576 f
    float*          Pp   = ws + 3145728;                      // 8,388,608 f partials
    unsigned short* Wp   = (unsigned short*)(ws + 11534336);  // 9,216,000 bf16
    float*          M    = ws + 16142336;                     // 32,768 f
    unsigned short* X0   = (unsigned short*)(ws + 16175104);  // [64][2048] bf16
    unsigned short* X1   = (unsigned short*)(ws + 16240640);  // [64][4096] bf16
    unsigned short* X2   = (unsigned short*)(ws + 16371712);  // [64][4096] bf16

    // weight prepack (conv1..conv4b)
    PPAll pa;
    const float* srcs[7] = {cw1, cw2a, cw2b, cw3a, cw3b, cw4a, cw4b};
    const unsigned long long doffs[7] = {0, 73728, 368640, 958464, 2138112, 4497408, 6856704};
    const int cins[7]  = {64, 128, 256, 256, 512, 512, 512};
    const int couts[7] = {128, 256, 256, 512, 512, 512, 512};
    const int ends[7]  = {8192, 40960, 106496, 237568, 499712, 761856, 1024000};
    for (int i = 0; i < 7; i++) {
        pa.src[i] = srcs[i]; pa.dstoff[i] = doffs[i];
        pa.cin[i] = cins[i]; pa.cout[i] = couts[i]; pa.end[i] = ends[i];
    }
    prepack<<<4000, 256, 0, stream>>>(pa, Wp);

    // conv0: x -> ActA [64][32][32][64] bf16 NHWC
    conv0_kernel<<<1024, 256, 0, stream>>>(x, cw0, cb0, ActA);
    // conv1 + relu + pool (KS=1): -> ActB [64][16][16][128]
    conv_mfma<64,128,32,2,2,1,8,4,1,true><<<dim3(1024,1,1),256,0,stream>>>(ActA, Wp+0, cb1, ActB);
    // conv2a (KS=2): -> ActA [64][16][16][256]
    conv_mfma<128,256,16,2,2,1,8,4,2,false><<<dim3(256,2,2),256,0,stream>>>(ActB, Wp+73728, cb2a, Pp);
    combine_nhwc<2, 16384, 256><<<4096,256,0,stream>>>(Pp, cb2a, ActA);
    // conv2b (KS=2) + pool in combine: -> ActB [64][8][8][256]
    conv_mfma<256,256,16,2,2,1,8,4,2,false><<<dim3(256,2,2),256,0,stream>>>(ActA, Wp+368640, cb2b, Pp);
    combine_pool<2, 16, 256><<<1024,256,0,stream>>>(Pp, cb2b, ActB);
    // conv3a (KS=4): -> ActA [64][8][8][512]
    conv_mfma<256,512,8,2,2,1,8,4,4,false><<<dim3(64,4,4),256,0,stream>>>(ActB, Wp+958464, cb3a, Pp);
    combine_nhwc<4, 4096, 512><<<2048,256,0,stream>>>(Pp, cb3a, ActA);
    // conv3b (KS=4): ksum tree + pool finish -> ActB [64][4][4][512]
    conv_mfma<512,512,8,2,2,1,8,4,4,false><<<dim3(64,4,4),256,0,stream>>>(ActA, Wp+2138112, cb3b, Pp);
    ksum4<2097152,1,1><<<2048,256,0,stream>>>(Pp);
    combine_pool<1, 8, 512><<<512,256,0,stream>>>(Pp, cb3b, ActB);
    // conv4a (KS=16): ksum tree + finish -> ActA [64][4][4][512]
    conv_mfma<512,512,4,2,2,2,4,4,16,false><<<dim3(16,4,16),256,0,stream>>>(ActB, Wp+4497408, cb4a, Pp);
    ksum4<524288,4,1><<<2048,256,0,stream>>>(Pp);
    ksum4<524288,1,4><<<512,256,0,stream>>>(Pp);
    combine_nhwc<1, 1024, 512><<<512,256,0,stream>>>(Pp, cb4a, ActA);
    // engram mask
    build_mask<<<64,128,0,stream>>>(y, btab, M);
    // conv4b (KS=16): ksum tree + mask/pool finish -> X0 [64][2048] bf16
    conv_mfma<512,512,4,2,2,2,4,4,16,false><<<dim3(16,4,16),256,0,stream>>>(ActA, Wp+6856704, cb4b, Pp);
    ksum4<524288,4,1><<<2048,256,0,stream>>>(Pp);
    ksum4<524288,1,4><<<512,256,0,stream>>>(Pp);
    combine4b<<<128,256,0,stream>>>(Pp, cb4b, M, X0);
    // classifier
    fc_mfma<2048,4096,4096,8><<<dim3(64,8),256,0,stream>>>(X0, fw1, Pp);
    fc_combine_bf16<4096,8><<<256,256,0,stream>>>(Pp, fb1, X1);
    fc_mfma<4096,4096,4096,8><<<dim3(64,8),256,0,stream>>>(X1, fw2, Pp);
    fc_combine_bf16<4096,8><<<256,256,0,stream>>>(Pp, fb2, X2);
    fc_mfma<4096,1024,1000,32><<<dim3(16,32),256,0,stream>>>(X2, fw3, Pp);
    ksum4<65536,8,1><<<512,256,0,stream>>>(Pp);
    fc3_combine<<<250,256,0,stream>>>(Pp, fb3, (float*)d_out);
}